// Round 1
// baseline (1000.905 us; speedup 1.0000x reference)
//
#include <hip/hip_runtime.h>
#include <hip/hip_bf16.h>

typedef unsigned short u16;
typedef unsigned int   u32;
typedef unsigned long long u64;

using short8 = __attribute__((ext_vector_type(8))) short;
using f32x4  = __attribute__((ext_vector_type(4))) float;
using u16x8  = __attribute__((ext_vector_type(8))) unsigned short;

#define AS_GLOBAL __attribute__((address_space(1)))
#define AS_LDS    __attribute__((address_space(3)))

// ---- bf16 helpers (manual RNE; avoids header type differences) ----
__device__ __forceinline__ u16 f2b(float x){
  u32 u = __float_as_uint(x);
  u32 r = (u + 0x7FFFu + ((u >> 16) & 1u)) >> 16;
  return (u16)r;
}
__device__ __forceinline__ float b2f(u16 h){ return __uint_as_float(((u32)h) << 16); }

__device__ __forceinline__ void gload16(u16* l, const u16* g){
  __builtin_amdgcn_global_load_lds((const AS_GLOBAL u32*)g, (AS_LDS u32*)l, 16, 0, 0);
}

__device__ __forceinline__ u64 umin64(u64 a, u64 b){ return a < b ? a : b; }

__device__ __forceinline__ u64 shfl_xor_u64(u64 v, int m){
  u32 lo = __shfl_xor((u32)v, m, 64);
  u32 hi = __shfl_xor((u32)(v >> 32), m, 64);
  return ((u64)hi << 32) | lo;
}

// ---- small prep kernels ----
__global__ void k_split(const float* __restrict__ w, u16* __restrict__ hi, u16* __restrict__ lo, int n){
  int i = blockIdx.x * 256 + threadIdx.x;
  if (i < n){
    float x = w[i];
    u16 h = f2b(x);
    hi[i] = h;
    lo[i] = f2b(x - b2f(h));
  }
}

__global__ void k_cvt(const float* __restrict__ w, u16* __restrict__ d, int n){
  int i = blockIdx.x * 256 + threadIdx.x;
  if (i < n) d[i] = f2b(w[i]);
}

__global__ void k_cnorm(const float* __restrict__ emb, float* __restrict__ cnorm){
  int v = blockIdx.x, lane = threadIdx.x;
  const float* r = emb + (size_t)v * 512;
  float s = 0.f;
  #pragma unroll
  for (int i = 0; i < 8; ++i){ float x = r[lane + i * 64]; s += x * x; }
  #pragma unroll
  for (int off = 32; off; off >>= 1) s += __shfl_down(s, off, 64);
  if (lane == 0) cnorm[v] = s;
}

// ---- transpose+split: src f32 [256 b][512 r][256 c] -> dh/dl bf16 [b][c][r] ----
// grid = 256*8*4 blocks, 256 threads
__global__ void k_tsplit(const float* __restrict__ src, u16* __restrict__ dh, u16* __restrict__ dl){
  __shared__ float t[64][65];
  const int bid = blockIdx.x;
  const int b  = bid >> 5;
  const int rb = (bid >> 2) & 7;
  const int cb = bid & 3;
  const float* s = src + ((size_t)b * 512 + (size_t)rb * 64) * 256 + cb * 64;
  const int tid = threadIdx.x;
  #pragma unroll
  for (int j = 0; j < 4; ++j){
    int fl = j * 256 + tid;           // 0..1023
    int r = fl >> 4, c4 = (fl & 15) * 4;
    float4 v = *(const float4*)(s + (size_t)r * 256 + c4);
    t[r][c4 + 0] = v.x; t[r][c4 + 1] = v.y; t[r][c4 + 2] = v.z; t[r][c4 + 3] = v.w;
  }
  __syncthreads();
  u16* oh = dh + ((size_t)b * 256 + (size_t)cb * 64) * 512 + rb * 64;
  u16* ol = dl + ((size_t)b * 256 + (size_t)cb * 64) * 512 + rb * 64;
  #pragma unroll
  for (int j = 0; j < 2; ++j){
    int fl = j * 256 + tid;           // 0..511
    int c = fl >> 3, r8 = (fl & 7) * 8;
    u16x8 hv, lv;
    #pragma unroll
    for (int i = 0; i < 8; ++i){
      float x = t[r8 + i][c];
      u16 h = f2b(x);
      hv[i] = h;
      lv[i] = f2b(x - b2f(h));
    }
    *(u16x8*)(oh + (size_t)c * 512 + r8) = hv;
    *(u16x8*)(ol + (size_t)c * 512 + r8) = lv;
  }
}

// ---- z_q gather: z_q[b][e][s] = emb[tok[b*256+s]][e] (f32, exact) ----
// grid = 1024 blocks x 64 threads
__global__ void k_zq(const u64* __restrict__ keys, const float* __restrict__ emb, float* __restrict__ zq){
  int sidx = blockIdx.x * 64 + threadIdx.x;   // 0..65535
  int b = sidx >> 8, s = sidx & 255;
  int v = (int)(u32)keys[sidx];
  const float4* er = (const float4*)(emb + (size_t)v * 512);
  float* o = zq + (size_t)b * 512 * 256 + s;
  #pragma unroll 4
  for (int e4 = 0; e4 < 128; ++e4){
    float4 vv = er[e4];
    o[(size_t)(e4 * 4 + 0) * 256] = vv.x;
    o[(size_t)(e4 * 4 + 1) * 256] = vv.y;
    o[(size_t)(e4 * 4 + 2) * 256] = vv.z;
    o[(size_t)(e4 * 4 + 3) * 256] = vv.w;
  }
}

// ---- the GEMM ----
// C_b[M x 256] = A[M x 512] * B_b[512 x 256], A row-major [M][K], B rows = [b*256+s][K].
// SPLIT: 3-product hi/lo bf16 (error ~2^-18 relative -> f32-grade scores).
// MODE 0/2: write C + bias (f32). MODE 1: score = cnorm[v]-2*acc, packed-u64 argmin.
// MODE 2: B rows gathered from Bh (=emb_hi) via token keys.
// LDS: [128][64] bf16 tiles, 16B-slot XOR swizzle (slot ^= row&7) applied on the
// global SOURCE address (global_load_lds writes linearly) and on the ds_read side.
template<bool SPLIT, int MODE>
__global__ __launch_bounds__(256, 2) void k_gemm(
    const u16* __restrict__ Ah, const u16* __restrict__ Al,
    const u16* __restrict__ Bh, const u16* __restrict__ Bl,
    const u64* __restrict__ gkeys,
    const float* __restrict__ bias,
    const float* __restrict__ cnorm,
    float* __restrict__ Cout,
    u64* __restrict__ okeys,
    int M, int mtbits)
{
  constexpr int K = 512;
  constexpr int NSEG = SPLIT ? 2 : 1;
  __shared__ __align__(16) u16 sA[NSEG][128 * 64];
  __shared__ __align__(16) u16 sB[NSEG][128 * 64];

  const int tid  = threadIdx.x;
  const int lane = tid & 63;
  const int wid  = tid >> 6;
  const int wm = wid >> 1, wn = wid & 1;

  const int bid = blockIdx.x;
  const int mt = bid & ((1 << mtbits) - 1);          // mt fastest: B-panel L2 reuse
  const int nt = (bid >> mtbits) & 1;
  const int b  = bid >> (mtbits + 1);
  const int m0 = mt * 128;
  const int n0 = nt * 128;
  const int bbase = b * 256;

  // staging descriptors (4 x 16B per thread per tile, source pre-unswizzled)
  const u16* ga[4]; const u16* gal[4];
  const u16* gb[4]; const u16* gbl[4];
  int ldso[4];
  #pragma unroll
  for (int i = 0; i < 4; ++i){
    int e = i * 256 + tid;          // 0..1023 tile 16B-slot index (lane-linear per wave)
    int r = e >> 3;
    int sl = (e & 7) ^ (r & 7);     // inverse swizzle on source
    ldso[i] = e * 8;
    size_t ao = (size_t)(m0 + r) * K + sl * 8;
    ga[i] = Ah + ao;
    if (SPLIT) gal[i] = Al + ao;
    size_t brow;
    if (MODE == 2) brow = (size_t)(u32)gkeys[bbase + n0 + r];
    else           brow = (size_t)(bbase + n0 + r);
    gb[i] = Bh + brow * K + sl * 8;
    if (SPLIT) gbl[i] = Bl + brow * K + sl * 8;
  }

  const f32x4 zero4 = {0.f, 0.f, 0.f, 0.f};
  f32x4 acc[4][4];
  #pragma unroll
  for (int i = 0; i < 4; ++i)
    #pragma unroll
    for (int j = 0; j < 4; ++j) acc[i][j] = zero4;

  // fragment read offsets (ushort units), swizzled
  int aoff[2][4], boff[2][4];
  #pragma unroll
  for (int ks = 0; ks < 2; ++ks)
    #pragma unroll
    for (int f = 0; f < 4; ++f){
      int rA = wm * 64 + f * 16 + (lane & 15);
      aoff[ks][f] = rA * 64 + (((ks * 4 + (lane >> 4)) ^ (rA & 7)) * 8);
      int rB = wn * 64 + f * 16 + (lane & 15);
      boff[ks][f] = rB * 64 + (((ks * 4 + (lane >> 4)) ^ (rB & 7)) * 8);
    }

  for (int kt = 0; kt < 8; ++kt){
    const int k0 = kt * 64;
    #pragma unroll
    for (int i = 0; i < 4; ++i){
      gload16(&sA[0][ldso[i]], ga[i] + k0);
      if (SPLIT) gload16(&sA[NSEG - 1][ldso[i]], gal[i] + k0);
      gload16(&sB[0][ldso[i]], gb[i] + k0);
      if (SPLIT) gload16(&sB[NSEG - 1][ldso[i]], gbl[i] + k0);
    }
    __syncthreads();
    #pragma unroll
    for (int ks = 0; ks < 2; ++ks){
      short8 ah[4], bh[4];
      #pragma unroll
      for (int f = 0; f < 4; ++f){
        ah[f] = *(const short8*)&sA[0][aoff[ks][f]];
        bh[f] = *(const short8*)&sB[0][boff[ks][f]];
      }
      #pragma unroll
      for (int fm = 0; fm < 4; ++fm)
        #pragma unroll
        for (int fn = 0; fn < 4; ++fn)
          acc[fm][fn] = __builtin_amdgcn_mfma_f32_16x16x32_bf16(ah[fm], bh[fn], acc[fm][fn], 0, 0, 0);
      if (SPLIT){
        short8 t[4];
        #pragma unroll
        for (int f = 0; f < 4; ++f) t[f] = *(const short8*)&sB[NSEG - 1][boff[ks][f]];
        #pragma unroll
        for (int fm = 0; fm < 4; ++fm)
          #pragma unroll
          for (int fn = 0; fn < 4; ++fn)
            acc[fm][fn] = __builtin_amdgcn_mfma_f32_16x16x32_bf16(ah[fm], t[fn], acc[fm][fn], 0, 0, 0);
        #pragma unroll
        for (int f = 0; f < 4; ++f) t[f] = *(const short8*)&sA[NSEG - 1][aoff[ks][f]];
        #pragma unroll
        for (int fm = 0; fm < 4; ++fm)
          #pragma unroll
          for (int fn = 0; fn < 4; ++fn)
            acc[fm][fn] = __builtin_amdgcn_mfma_f32_16x16x32_bf16(t[fm], bh[fn], acc[fm][fn], 0, 0, 0);
      }
    }
    __syncthreads();
  }

  if (MODE != 1){
    const int row0 = m0 + wm * 64;
    const int col  = n0 + wn * 64 + (lane & 15);
    float* Cb = Cout + (size_t)b * M * 256;
    #pragma unroll
    for (int fm = 0; fm < 4; ++fm){
      #pragma unroll
      for (int j = 0; j < 4; ++j){
        int row = row0 + fm * 16 + (lane >> 4) * 4 + j;
        float bi = bias[row];
        #pragma unroll
        for (int fn = 0; fn < 4; ++fn)
          Cb[(size_t)row * 256 + col + fn * 16] = acc[fm][fn][j] + bi;
      }
    }
  } else {
    u64 best[4];
    #pragma unroll
    for (int fn = 0; fn < 4; ++fn){
      u64 bk = ~0ull;
      #pragma unroll
      for (int fm = 0; fm < 4; ++fm){
        #pragma unroll
        for (int j = 0; j < 4; ++j){
          int v = m0 + wm * 64 + fm * 16 + (lane >> 4) * 4 + j;
          float sc = cnorm[v] - 2.0f * acc[fm][fn][j];
          u32 o = __float_as_uint(sc);
          o = (o & 0x80000000u) ? ~o : (o | 0x80000000u);   // order-preserving map
          u64 key = ((u64)o << 32) | (u32)v;                // tie -> smallest v (numpy)
          bk = umin64(bk, key);
        }
      }
      bk = umin64(bk, shfl_xor_u64(bk, 16));
      bk = umin64(bk, shfl_xor_u64(bk, 32));
      best[fn] = bk;
    }
    __syncthreads();
    u64* kbuf = (u64*)&sA[0][0];     // reuse LDS (all tile reads done)
    if (lane < 16){
      #pragma unroll
      for (int fn = 0; fn < 4; ++fn)
        kbuf[wm * 128 + wn * 64 + fn * 16 + lane] = best[fn];
    }
    __syncthreads();
    if (tid < 128){
      u64 k2 = umin64(kbuf[tid], kbuf[128 + tid]);
      atomicMin((unsigned long long*)(okeys + (size_t)bbase + n0 + tid), (unsigned long long)k2);
    }
  }
}

extern "C" void kernel_launch(void* const* d_in, const int* in_sizes, int n_in,
                              void* d_out, int out_size, void* d_ws, size_t ws_size,
                              hipStream_t stream){
  const float* x      = (const float*)d_in[0];
  const float* pre_w  = (const float*)d_in[1];
  const float* pre_b  = (const float*)d_in[2];
  const float* emb    = (const float*)d_in[3];
  const float* post_w = (const float*)d_in[4];
  const float* post_b = (const float*)d_in[5];

  float* z_out   = (float*)d_out;              // [256][512][256]
  float* zq_out  = z_out + 33554432;           // [256][512][256]
  float* rec_out = z_out + 67108864;           // [256][512][256]

  char* w = (char*)d_ws;
  u16* prew_hi = (u16*)(w);                    // 512KB
  u16* prew_lo = (u16*)(w + 524288);           // 512KB
  u16* postw_b = (u16*)(w + 1048576);          // 512KB
  u16* emb_hi  = (u16*)(w + 1572864);          // 4MB
  u16* emb_lo  = (u16*)(w + 5767168);          // 4MB
  float* cnorm = (float*)(w + 9961472);        // 16KB
  u64* keys    = (u64*)(w + 9977856);          // 512KB
  u16* xh      = (u16*)(w + 10502144);         // 64MB [65536][512]
  u16* xl      = (u16*)(w + 77611008);         // 64MB  (total ~138MB)
  u16* zh = xh; u16* zl = xl;                  // z splits alias x splits (disjoint lifetime)

  k_split<<<1024, 256, 0, stream>>>(pre_w, prew_hi, prew_lo, 262144);
  k_split<<<8192, 256, 0, stream>>>(emb, emb_hi, emb_lo, 2097152);
  k_cvt  <<<1024, 256, 0, stream>>>(post_w, postw_b, 262144);
  k_cnorm<<<4096, 64, 0, stream>>>(emb, cnorm);
  hipMemsetAsync(keys, 0xFF, 65536 * sizeof(u64), stream);

  // x [b][c][s] -> xh/xl [b][s][c]
  k_tsplit<<<8192, 256, 0, stream>>>(x, xh, xl);

  // GEMM1: z = pre_w * x + pre_b   (split, f32-grade)
  k_gemm<true, 0><<<256 * 2 * 4, 256, 0, stream>>>(prew_hi, prew_lo, xh, xl,
      nullptr, pre_b, nullptr, z_out, nullptr, 512, 2);

  // z [b][e][s] -> zh/zl [b][s][e]
  k_tsplit<<<8192, 256, 0, stream>>>(z_out, zh, zl);

  // GEMM2: scores + fused argmin -> keys
  k_gemm<true, 1><<<256 * 2 * 32, 256, 0, stream>>>(emb_hi, emb_lo, zh, zl,
      nullptr, nullptr, cnorm, nullptr, keys, 4096, 5);

  // z_q gather (exact f32)
  k_zq<<<1024, 64, 0, stream>>>(keys, emb, zq_out);

  // GEMM3: rec = post_w * z_q + post_b  (B staged by gathering emb_hi rows via tokens)
  k_gemm<false, 2><<<256 * 2 * 4, 256, 0, stream>>>(postw_b, nullptr, emb_hi, nullptr,
      keys, post_b, nullptr, rec_out, nullptr, 512, 2);
}

// Round 2
// 592.637 us; speedup vs baseline: 1.6889x; 1.6889x over previous
//
#include <hip/hip_runtime.h>
#include <hip/hip_bf16.h>

typedef unsigned short u16;
typedef unsigned int   u32;
typedef unsigned long long u64;

using short8 = __attribute__((ext_vector_type(8))) short;
using f32x4  = __attribute__((ext_vector_type(4))) float;
using u16x8  = __attribute__((ext_vector_type(8))) unsigned short;

#define AS_GLOBAL __attribute__((address_space(1)))
#define AS_LDS    __attribute__((address_space(3)))

// ---- bf16 helpers (manual RNE) ----
__device__ __forceinline__ u16 f2b(float x){
  u32 u = __float_as_uint(x);
  u32 r = (u + 0x7FFFu + ((u >> 16) & 1u)) >> 16;
  return (u16)r;
}
__device__ __forceinline__ float b2f(u16 h){ return __uint_as_float(((u32)h) << 16); }

__device__ __forceinline__ void gload16(u16* l, const u16* g){
  __builtin_amdgcn_global_load_lds((const AS_GLOBAL u32*)g, (AS_LDS u32*)l, 16, 0, 0);
}

__device__ __forceinline__ u64 umin64(u64 a, u64 b){ return a < b ? a : b; }

__device__ __forceinline__ u64 shfl_xor_u64(u64 v, int m){
  u32 lo = __shfl_xor((u32)v, m, 64);
  u32 hi = __shfl_xor((u32)(v >> 32), m, 64);
  return ((u64)hi << 32) | lo;
}

// ---- prep kernels ----
__global__ void k_cvt(const float* __restrict__ w, u16* __restrict__ d, int n){
  int i = blockIdx.x * 256 + threadIdx.x;
  if (i < n) d[i] = f2b(w[i]);
}

__global__ void k_cnorm(const float* __restrict__ emb, float* __restrict__ cnorm){
  int v = blockIdx.x, lane = threadIdx.x;
  const float* r = emb + (size_t)v * 512;
  float s = 0.f;
  #pragma unroll
  for (int i = 0; i < 8; ++i){ float x = r[lane + i * 64]; s += x * x; }
  #pragma unroll
  for (int off = 32; off; off >>= 1) s += __shfl_down(s, off, 64);
  if (lane == 0) cnorm[v] = s;
}

// ---- transpose+convert: src f32 [256 b][512 r][256 c] -> d bf16 [b][c][r] ----
// grid = 256*8*4 blocks, 256 threads
__global__ void k_tcvt(const float* __restrict__ src, u16* __restrict__ d){
  __shared__ float t[64][65];
  const int bid = blockIdx.x;
  const int b  = bid >> 5;
  const int rb = (bid >> 2) & 7;
  const int cb = bid & 3;
  const float* s = src + ((size_t)b * 512 + (size_t)rb * 64) * 256 + cb * 64;
  const int tid = threadIdx.x;
  #pragma unroll
  for (int j = 0; j < 4; ++j){
    int fl = j * 256 + tid;           // 0..1023
    int r = fl >> 4, c4 = (fl & 15) * 4;
    float4 v = *(const float4*)(s + (size_t)r * 256 + c4);
    t[r][c4 + 0] = v.x; t[r][c4 + 1] = v.y; t[r][c4 + 2] = v.z; t[r][c4 + 3] = v.w;
  }
  __syncthreads();
  u16* o = d + ((size_t)b * 256 + (size_t)cb * 64) * 512 + rb * 64;
  #pragma unroll
  for (int j = 0; j < 2; ++j){
    int fl = j * 256 + tid;           // 0..511
    int c = fl >> 3, r8 = (fl & 7) * 8;
    u16x8 hv;
    #pragma unroll
    for (int i = 0; i < 8; ++i) hv[i] = f2b(t[r8 + i][c]);
    *(u16x8*)(o + (size_t)c * 512 + r8) = hv;
  }
}

// ---- z_q gather: z_q[b][e][s] = emb[tok[b*256+s]][e] (f32, exact) ----
__global__ void k_zq(const u64* __restrict__ keys, const float* __restrict__ emb, float* __restrict__ zq){
  int sidx = blockIdx.x * 64 + threadIdx.x;   // 0..65535
  int b = sidx >> 8, s = sidx & 255;
  int v = (int)(u32)keys[sidx];
  const float4* er = (const float4*)(emb + (size_t)v * 512);
  float* o = zq + (size_t)b * 512 * 256 + s;
  #pragma unroll 4
  for (int e4 = 0; e4 < 128; ++e4){
    float4 vv = er[e4];
    o[(size_t)(e4 * 4 + 0) * 256] = vv.x;
    o[(size_t)(e4 * 4 + 1) * 256] = vv.y;
    o[(size_t)(e4 * 4 + 2) * 256] = vv.z;
    o[(size_t)(e4 * 4 + 3) * 256] = vv.w;
  }
}

// ---- the GEMM (pure bf16) ----
// C_b[M x 256] = A[M x 512] * B_b[512 x 256], A row-major [M][K], B rows = [b*256+s][K].
// MODE 0: write C + bias (f32). MODE 1: score = cnorm[v]-2*acc, packed-u64 argmin.
// MODE 2: B rows gathered from Bh (=emb bf16) via token keys.
// LDS [128][64] bf16 tiles, 16B-slot XOR swizzle (slot ^= row&7) via pre-unswizzled
// global source (global_load_lds writes linearly) + swizzled ds_read.
// XCD-chunked block swizzle: grid %8==0 for all launches.
template<int MODE>
__global__ __launch_bounds__(256, 4) void k_gemm(
    const u16* __restrict__ Ah,
    const u16* __restrict__ Bh,
    const u64* __restrict__ gkeys,
    const float* __restrict__ bias,
    const float* __restrict__ cnorm,
    float* __restrict__ Cout,
    u64* __restrict__ okeys,
    int M, int mtbits)
{
  constexpr int K = 512;
  __shared__ __align__(16) u16 sA[128 * 64];
  __shared__ __align__(16) u16 sB[128 * 64];

  const int tid  = threadIdx.x;
  const int lane = tid & 63;
  const int wid  = tid >> 6;
  const int wm = wid >> 1, wn = wid & 1;

  // XCD-aware swizzle: contiguous logical chunk per XCD
  const int nwg = gridDim.x;
  const int chunk = nwg >> 3;
  const int pb = blockIdx.x;
  const int bid = (pb & 7) * chunk + (pb >> 3);

  const int mt = bid & ((1 << mtbits) - 1);          // mt fastest: B-panel L2 reuse
  const int nt = (bid >> mtbits) & 1;
  const int b  = bid >> (mtbits + 1);
  const int m0 = mt * 128;
  const int n0 = nt * 128;
  const int bbase = b * 256;

  // staging descriptors (4 x 16B per thread per tile for each of A,B)
  const u16* ga[4];
  const u16* gb[4];
  int ldso[4];
  #pragma unroll
  for (int i = 0; i < 4; ++i){
    int e = i * 256 + tid;          // 0..1023 tile 16B-slot index (lane-linear per wave)
    int r = e >> 3;
    int sl = (e & 7) ^ (r & 7);     // inverse swizzle on source
    ldso[i] = e * 8;
    ga[i] = Ah + (size_t)(m0 + r) * K + sl * 8;
    size_t brow;
    if (MODE == 2) brow = (size_t)(u32)gkeys[bbase + n0 + r];
    else           brow = (size_t)(bbase + n0 + r);
    gb[i] = Bh + brow * K + sl * 8;
  }

  const f32x4 zero4 = {0.f, 0.f, 0.f, 0.f};
  f32x4 acc[4][4];
  #pragma unroll
  for (int i = 0; i < 4; ++i)
    #pragma unroll
    for (int j = 0; j < 4; ++j) acc[i][j] = zero4;

  // fragment read offsets (ushort units), swizzled
  int aoff[2][4], boff[2][4];
  #pragma unroll
  for (int ks = 0; ks < 2; ++ks)
    #pragma unroll
    for (int f = 0; f < 4; ++f){
      int rA = wm * 64 + f * 16 + (lane & 15);
      aoff[ks][f] = rA * 64 + (((ks * 4 + (lane >> 4)) ^ (rA & 7)) * 8);
      int rB = wn * 64 + f * 16 + (lane & 15);
      boff[ks][f] = rB * 64 + (((ks * 4 + (lane >> 4)) ^ (rB & 7)) * 8);
    }

  for (int kt = 0; kt < 8; ++kt){
    const int k0 = kt * 64;
    #pragma unroll
    for (int i = 0; i < 4; ++i){
      gload16(&sA[ldso[i]], ga[i] + k0);
      gload16(&sB[ldso[i]], gb[i] + k0);
    }
    __syncthreads();
    #pragma unroll
    for (int ks = 0; ks < 2; ++ks){
      short8 ah[4], bh[4];
      #pragma unroll
      for (int f = 0; f < 4; ++f){
        ah[f] = *(const short8*)&sA[aoff[ks][f]];
        bh[f] = *(const short8*)&sB[boff[ks][f]];
      }
      #pragma unroll
      for (int fm = 0; fm < 4; ++fm)
        #pragma unroll
        for (int fn = 0; fn < 4; ++fn)
          acc[fm][fn] = __builtin_amdgcn_mfma_f32_16x16x32_bf16(ah[fm], bh[fn], acc[fm][fn], 0, 0, 0);
    }
    __syncthreads();
  }

  if (MODE != 1){
    const int row0 = m0 + wm * 64;
    const int col  = n0 + wn * 64 + (lane & 15);
    float* Cb = Cout + (size_t)b * M * 256;
    #pragma unroll
    for (int fm = 0; fm < 4; ++fm){
      #pragma unroll
      for (int j = 0; j < 4; ++j){
        int row = row0 + fm * 16 + (lane >> 4) * 4 + j;
        float bi = bias[row];
        #pragma unroll
        for (int fn = 0; fn < 4; ++fn)
          Cb[(size_t)row * 256 + col + fn * 16] = acc[fm][fn][j] + bi;
      }
    }
  } else {
    u64 best[4];
    #pragma unroll
    for (int fn = 0; fn < 4; ++fn){
      u64 bk = ~0ull;
      #pragma unroll
      for (int fm = 0; fm < 4; ++fm){
        #pragma unroll
        for (int j = 0; j < 4; ++j){
          int v = m0 + wm * 64 + fm * 16 + (lane >> 4) * 4 + j;
          float sc = cnorm[v] - 2.0f * acc[fm][fn][j];
          u32 o = __float_as_uint(sc);
          o = (o & 0x80000000u) ? ~o : (o | 0x80000000u);   // order-preserving map
          u64 key = ((u64)o << 32) | (u32)v;                // tie -> smallest v (numpy)
          bk = umin64(bk, key);
        }
      }
      bk = umin64(bk, shfl_xor_u64(bk, 16));
      bk = umin64(bk, shfl_xor_u64(bk, 32));
      best[fn] = bk;
    }
    __syncthreads();
    u64* kbuf = (u64*)&sA[0];        // reuse LDS (all tile reads done)
    if (lane < 16){
      #pragma unroll
      for (int fn = 0; fn < 4; ++fn)
        kbuf[wm * 128 + wn * 64 + fn * 16 + lane] = best[fn];
    }
    __syncthreads();
    if (tid < 128){
      u64 k2 = umin64(kbuf[tid], kbuf[128 + tid]);
      atomicMin((unsigned long long*)(okeys + (size_t)bbase + n0 + tid), (unsigned long long)k2);
    }
  }
}

extern "C" void kernel_launch(void* const* d_in, const int* in_sizes, int n_in,
                              void* d_out, int out_size, void* d_ws, size_t ws_size,
                              hipStream_t stream){
  const float* x      = (const float*)d_in[0];
  const float* pre_w  = (const float*)d_in[1];
  const float* pre_b  = (const float*)d_in[2];
  const float* emb    = (const float*)d_in[3];
  const float* post_w = (const float*)d_in[4];
  const float* post_b = (const float*)d_in[5];

  float* z_out   = (float*)d_out;              // [256][512][256]
  float* zq_out  = z_out + 33554432;           // [256][512][256]
  float* rec_out = z_out + 67108864;           // [256][512][256]

  char* w = (char*)d_ws;
  u16* prew_b  = (u16*)(w);                    // 512KB
  u16* postw_b = (u16*)(w + 524288);           // 512KB
  u16* emb_b   = (u16*)(w + 1048576);          // 4MB
  float* cnorm = (float*)(w + 5242880);        // 16KB
  u64* keys    = (u64*)(w + 5259264);          // 512KB
  u16* xb      = (u16*)(w + 5783552);          // 64MB [65536][512] bf16
  u16* zb = xb;                                // z^T bf16 aliases xb (disjoint lifetime)

  k_cvt  <<<1024, 256, 0, stream>>>(pre_w, prew_b, 262144);
  k_cvt  <<<1024, 256, 0, stream>>>(post_w, postw_b, 262144);
  k_cvt  <<<8192, 256, 0, stream>>>(emb, emb_b, 2097152);
  k_cnorm<<<4096, 64, 0, stream>>>(emb, cnorm);
  hipMemsetAsync(keys, 0xFF, 65536 * sizeof(u64), stream);

  // x [b][c][s] -> xb [b][s][c]
  k_tcvt<<<8192, 256, 0, stream>>>(x, xb);

  // GEMM1: z = pre_w * x + pre_b
  k_gemm<0><<<256 * 2 * 4, 256, 0, stream>>>(prew_b, xb,
      nullptr, pre_b, nullptr, z_out, nullptr, 512, 2);

  // z [b][e][s] -> zb [b][s][e]
  k_tcvt<<<8192, 256, 0, stream>>>(z_out, zb);

  // GEMM2: scores + fused argmin -> keys
  k_gemm<1><<<256 * 2 * 32, 256, 0, stream>>>(emb_b, zb,
      nullptr, nullptr, cnorm, nullptr, keys, 4096, 5);

  // z_q gather (exact f32)
  k_zq<<<1024, 64, 0, stream>>>(keys, emb, zq_out);

  // GEMM3: rec = post_w * z_q + post_b  (B staged by gathering emb_b rows via tokens)
  k_gemm<2><<<256 * 2 * 4, 256, 0, stream>>>(postw_b, emb_b,
      keys, post_b, nullptr, rec_out, nullptr, 512, 2);
}

// Round 3
// 548.863 us; speedup vs baseline: 1.8236x; 1.0798x over previous
//
#include <hip/hip_runtime.h>
#include <hip/hip_bf16.h>

typedef unsigned short u16;
typedef unsigned int   u32;
typedef unsigned long long u64;

using short8 = __attribute__((ext_vector_type(8))) short;
using f32x4  = __attribute__((ext_vector_type(4))) float;
using u16x8  = __attribute__((ext_vector_type(8))) unsigned short;

#define AS_GLOBAL __attribute__((address_space(1)))
#define AS_LDS    __attribute__((address_space(3)))

// ---- bf16 helpers (manual RNE) ----
__device__ __forceinline__ u16 f2b(float x){
  u32 u = __float_as_uint(x);
  u32 r = (u + 0x7FFFu + ((u >> 16) & 1u)) >> 16;
  return (u16)r;
}
__device__ __forceinline__ float b2f(u16 h){ return __uint_as_float(((u32)h) << 16); }

__device__ __forceinline__ void gload16(u16* l, const u16* g){
  __builtin_amdgcn_global_load_lds((const AS_GLOBAL u32*)g, (AS_LDS u32*)l, 16, 0, 0);
}

__device__ __forceinline__ u64 umin64(u64 a, u64 b){ return a < b ? a : b; }

__device__ __forceinline__ u64 shfl_xor_u64(u64 v, int m){
  u32 lo = __shfl_xor((u32)v, m, 64);
  u32 hi = __shfl_xor((u32)(v >> 32), m, 64);
  return ((u64)hi << 32) | lo;
}

__device__ __forceinline__ void waitv4(){ asm volatile("s_waitcnt vmcnt(4)" ::: "memory"); }
__device__ __forceinline__ void waitv0(){ asm volatile("s_waitcnt vmcnt(0)" ::: "memory"); }

// ---- prep kernels ----
__global__ void k_cvt(const float* __restrict__ w, u16* __restrict__ d, int n){
  int i = blockIdx.x * 256 + threadIdx.x;
  if (i < n) d[i] = f2b(w[i]);
}

__global__ void k_cnorm(const float* __restrict__ emb, float* __restrict__ cnorm){
  int v = blockIdx.x, lane = threadIdx.x;
  const float* r = emb + (size_t)v * 512;
  float s = 0.f;
  #pragma unroll
  for (int i = 0; i < 8; ++i){ float x = r[lane + i * 64]; s += x * x; }
  #pragma unroll
  for (int off = 32; off; off >>= 1) s += __shfl_down(s, off, 64);
  if (lane == 0) cnorm[v] = s;
}

// ---- transpose+convert: src f32 [256 b][512 r][256 c] -> d bf16 [b][c][r] ----
__global__ void k_tcvt(const float* __restrict__ src, u16* __restrict__ d){
  __shared__ float t[64][65];
  const int bid = blockIdx.x;
  const int b  = bid >> 5;
  const int rb = (bid >> 2) & 7;
  const int cb = bid & 3;
  const float* s = src + ((size_t)b * 512 + (size_t)rb * 64) * 256 + cb * 64;
  const int tid = threadIdx.x;
  #pragma unroll
  for (int j = 0; j < 4; ++j){
    int fl = j * 256 + tid;
    int r = fl >> 4, c4 = (fl & 15) * 4;
    float4 v = *(const float4*)(s + (size_t)r * 256 + c4);
    t[r][c4 + 0] = v.x; t[r][c4 + 1] = v.y; t[r][c4 + 2] = v.z; t[r][c4 + 3] = v.w;
  }
  __syncthreads();
  u16* o = d + ((size_t)b * 256 + (size_t)cb * 64) * 512 + rb * 64;
  #pragma unroll
  for (int j = 0; j < 2; ++j){
    int fl = j * 256 + tid;
    int c = fl >> 3, r8 = (fl & 7) * 8;
    u16x8 hv;
    #pragma unroll
    for (int i = 0; i < 8; ++i) hv[i] = f2b(t[r8 + i][c]);
    *(u16x8*)(o + (size_t)c * 512 + r8) = hv;
  }
}

// ---- z_q gather ----
__global__ void k_zq(const u64* __restrict__ keys, const float* __restrict__ emb, float* __restrict__ zq){
  int sidx = blockIdx.x * 64 + threadIdx.x;
  int b = sidx >> 8, s = sidx & 255;
  int v = (int)(u32)keys[sidx];
  const float4* er = (const float4*)(emb + (size_t)v * 512);
  float* o = zq + (size_t)b * 512 * 256 + s;
  #pragma unroll 4
  for (int e4 = 0; e4 < 128; ++e4){
    float4 vv = er[e4];
    o[(size_t)(e4 * 4 + 0) * 256] = vv.x;
    o[(size_t)(e4 * 4 + 1) * 256] = vv.y;
    o[(size_t)(e4 * 4 + 2) * 256] = vv.z;
    o[(size_t)(e4 * 4 + 3) * 256] = vv.w;
  }
}

// ---- small GEMM (round-2 proven 128x128 2-phase): GEMM1 & GEMM3 ----
template<int MODE>
__global__ __launch_bounds__(256, 4) void k_gemm(
    const u16* __restrict__ Ah,
    const u16* __restrict__ Bh,
    const u64* __restrict__ gkeys,
    const float* __restrict__ bias,
    const float* __restrict__ cnorm,
    float* __restrict__ Cout,
    u64* __restrict__ okeys,
    int M, int mtbits)
{
  constexpr int K = 512;
  __shared__ __align__(16) u16 sA[128 * 64];
  __shared__ __align__(16) u16 sB[128 * 64];

  const int tid  = threadIdx.x;
  const int lane = tid & 63;
  const int wid  = tid >> 6;
  const int wm = wid >> 1, wn = wid & 1;

  const int nwg = gridDim.x;
  const int chunk = nwg >> 3;
  const int pb = blockIdx.x;
  const int bid = (pb & 7) * chunk + (pb >> 3);

  const int mt = bid & ((1 << mtbits) - 1);
  const int nt = (bid >> mtbits) & 1;
  const int b  = bid >> (mtbits + 1);
  const int m0 = mt * 128;
  const int n0 = nt * 128;
  const int bbase = b * 256;

  const u16* ga[4];
  const u16* gb[4];
  int ldso[4];
  #pragma unroll
  for (int i = 0; i < 4; ++i){
    int e = i * 256 + tid;
    int r = e >> 3;
    int sl = (e & 7) ^ (r & 7);
    ldso[i] = e * 8;
    ga[i] = Ah + (size_t)(m0 + r) * K + sl * 8;
    size_t brow;
    if (MODE == 2) brow = (size_t)(u32)gkeys[bbase + n0 + r];
    else           brow = (size_t)(bbase + n0 + r);
    gb[i] = Bh + brow * K + sl * 8;
  }

  const f32x4 zero4 = {0.f, 0.f, 0.f, 0.f};
  f32x4 acc[4][4];
  #pragma unroll
  for (int i = 0; i < 4; ++i)
    #pragma unroll
    for (int j = 0; j < 4; ++j) acc[i][j] = zero4;

  int aoff[2][4], boff[2][4];
  #pragma unroll
  for (int ks = 0; ks < 2; ++ks)
    #pragma unroll
    for (int f = 0; f < 4; ++f){
      int rA = wm * 64 + f * 16 + (lane & 15);
      aoff[ks][f] = rA * 64 + (((ks * 4 + (lane >> 4)) ^ (rA & 7)) * 8);
      int rB = wn * 64 + f * 16 + (lane & 15);
      boff[ks][f] = rB * 64 + (((ks * 4 + (lane >> 4)) ^ (rB & 7)) * 8);
    }

  for (int kt = 0; kt < 8; ++kt){
    const int k0 = kt * 64;
    #pragma unroll
    for (int i = 0; i < 4; ++i){
      gload16(&sA[ldso[i]], ga[i] + k0);
      gload16(&sB[ldso[i]], gb[i] + k0);
    }
    __syncthreads();
    #pragma unroll
    for (int ks = 0; ks < 2; ++ks){
      short8 ah[4], bh[4];
      #pragma unroll
      for (int f = 0; f < 4; ++f){
        ah[f] = *(const short8*)&sA[aoff[ks][f]];
        bh[f] = *(const short8*)&sB[boff[ks][f]];
      }
      #pragma unroll
      for (int fm = 0; fm < 4; ++fm)
        #pragma unroll
        for (int fn = 0; fn < 4; ++fn)
          acc[fm][fn] = __builtin_amdgcn_mfma_f32_16x16x32_bf16(ah[fm], bh[fn], acc[fm][fn], 0, 0, 0);
    }
    __syncthreads();
  }

  if (MODE != 1){
    const int row0 = m0 + wm * 64;
    const int col  = n0 + wn * 64 + (lane & 15);
    float* Cb = Cout + (size_t)b * M * 256;
    #pragma unroll
    for (int fm = 0; fm < 4; ++fm){
      #pragma unroll
      for (int j = 0; j < 4; ++j){
        int row = row0 + fm * 16 + (lane >> 4) * 4 + j;
        float bi = bias[row];
        #pragma unroll
        for (int fn = 0; fn < 4; ++fn)
          Cb[(size_t)row * 256 + col + fn * 16] = acc[fm][fn][j] + bi;
      }
    }
  }
}

// ---- GEMM2: 256x256x(K=512) phase-pipelined, fused score+argmin ----
// A = emb_b [4096][512], B = zb rows [bbase..bbase+255][512].
// 8 waves (2 wm x 4 wn), per-wave 128x64 output, acc[8][4] f32x4.
// LDS [2 buf][A 256x64 | B 256x64] = 128KB, slot^row&7 swizzle (proven 0-conflict).
// 4 phases per K-tile: (fmL,fnL),(fmL,fnH),(fmH,fnH),(fmH,fnL).
// Stage stream (per phase, 2 gloads/wave): ph0->(t+1).AfmH, ph1->(t+1).BfnL,
// ph2->(t+2).AfmL, ph3->(t+2).BfnH.  Region safety: AfmL read only in ph0
// (regs reused ph1), BfnH read only ph1 (reused ph2), AfmH ph2 (reused ph3),
// BfnL ph0+ph3 -> each stage's dest was freed >=1 barrier before issue.
// Boundary: counted vmcnt(4) (never 0 until final tile) + raw s_barrier.
__global__ __launch_bounds__(512, 2) void k_gemm2(
    const u16* __restrict__ Ah,
    const u16* __restrict__ Bh,
    const float* __restrict__ cnorm,
    u64* __restrict__ okeys)
{
  __shared__ __align__(16) u16 lds[2][32768];   // [buf][A(16384) | B(16384)]

  const int tid  = threadIdx.x;
  const int lane = tid & 63;
  const int wid  = tid >> 6;
  const int wm   = wid >> 2;
  const int wn   = wid & 3;

  const int nwg = gridDim.x;
  const int chunk = nwg >> 3;
  const int pb  = blockIdx.x;
  const int bid = (pb & 7) * chunk + (pb >> 3);
  const int mt = bid & 15;
  const int b  = bid >> 4;
  const int m0 = mt * 256;
  const int bbase = b * 256;

  // staging constants: 8-row 1KB chunks, 2 per wave per 16KB region
  const int l8 = lane >> 3;
  const int sl = (lane & 7) ^ l8;                       // pre-unswizzled source slot
  const int arb = (wid < 4) ? wid * 16 : 128 + (wid - 4) * 16;  // AfmL rows {0-63,128-191}
  const int brb = (wid >> 1) * 64 + (wid & 1) * 16;             // BfnL rows {0-31,64-95,...}

  const u16* srcA0 = Ah + (size_t)(m0 + arb + l8) * 512 + sl * 8;
  const u16* srcA1 = srcA0 + 8 * 512;
  const u16* srcB0 = Bh + (size_t)(bbase + brb + l8) * 512 + sl * 8;
  const u16* srcB1 = srcB0 + 8 * 512;
  const int dA0 = arb * 64 + lane * 8;
  const int dA1 = dA0 + 512;
  const int dB0 = 16384 + brb * 64 + lane * 8;
  const int dB1 = dB0 + 512;

#define STG_AFML(p, kk) { gload16(&lds[p][dA0], srcA0 + (kk)); gload16(&lds[p][dA1], srcA1 + (kk)); }
#define STG_AFMH(p, kk) { gload16(&lds[p][dA0 + 4096], srcA0 + 32768 + (kk)); gload16(&lds[p][dA1 + 4096], srcA1 + 32768 + (kk)); }
#define STG_BFNL(p, kk) { gload16(&lds[p][dB0], srcB0 + (kk)); gload16(&lds[p][dB1], srcB1 + (kk)); }
#define STG_BFNH(p, kk) { gload16(&lds[p][dB0 + 2048], srcB0 + 16384 + (kk)); gload16(&lds[p][dB1 + 2048], srcB1 + 16384 + (kk)); }

  int aoff[2][8], boff[2][4];
  #pragma unroll
  for (int ks = 0; ks < 2; ++ks){
    #pragma unroll
    for (int f = 0; f < 8; ++f){
      int rA = wm * 128 + f * 16 + (lane & 15);
      aoff[ks][f] = rA * 64 + (((ks * 4 + (lane >> 4)) ^ (rA & 7)) * 8);
    }
    #pragma unroll
    for (int f = 0; f < 4; ++f){
      int rB = wn * 64 + f * 16 + (lane & 15);
      boff[ks][f] = 16384 + rB * 64 + (((ks * 4 + (lane >> 4)) ^ (rB & 7)) * 8);
    }
  }

  const f32x4 zero4 = {0.f, 0.f, 0.f, 0.f};
  f32x4 acc[8][4];
  #pragma unroll
  for (int i = 0; i < 8; ++i)
    #pragma unroll
    for (int j = 0; j < 4; ++j) acc[i][j] = zero4;

  // prologue: tile0 fully + tile1 {AfmL, BfnH}
  STG_AFML(0, 0) STG_AFMH(0, 0) STG_BFNL(0, 0) STG_BFNH(0, 0)
  STG_AFML(1, 64) STG_BFNH(1, 64)
  waitv4();
  __builtin_amdgcn_s_barrier();
  __builtin_amdgcn_sched_barrier(0);

  for (int t = 0; t < 8; ++t){
    const int bc = t & 1;
    const int bn = bc ^ 1;
    const u16* cb = &lds[bc][0];
    const int kn1 = (t + 1) * 64, kn2 = (t + 2) * 64;
    short8 ah[4][2], bh[2][2];

    // ---- ph0: (fmL, fnL) ----
    if (t < 7) STG_AFMH(bn, kn1)
    #pragma unroll
    for (int f = 0; f < 4; ++f){ ah[f][0] = *(const short8*)&cb[aoff[0][f]]; ah[f][1] = *(const short8*)&cb[aoff[1][f]]; }
    #pragma unroll
    for (int f = 0; f < 2; ++f){ bh[f][0] = *(const short8*)&cb[boff[0][f]]; bh[f][1] = *(const short8*)&cb[boff[1][f]]; }
    __builtin_amdgcn_s_setprio(1);
    #pragma unroll
    for (int fm = 0; fm < 4; ++fm)
      #pragma unroll
      for (int fn = 0; fn < 2; ++fn){
        acc[fm][fn] = __builtin_amdgcn_mfma_f32_16x16x32_bf16(ah[fm][0], bh[fn][0], acc[fm][fn], 0, 0, 0);
        acc[fm][fn] = __builtin_amdgcn_mfma_f32_16x16x32_bf16(ah[fm][1], bh[fn][1], acc[fm][fn], 0, 0, 0);
      }
    __builtin_amdgcn_s_setprio(0);
    __builtin_amdgcn_sched_barrier(0);
    __builtin_amdgcn_s_barrier();
    __builtin_amdgcn_sched_barrier(0);

    // ---- ph1: (fmL, fnH) ----
    if (t < 7) STG_BFNL(bn, kn1)
    #pragma unroll
    for (int f = 0; f < 2; ++f){ bh[f][0] = *(const short8*)&cb[boff[0][2 + f]]; bh[f][1] = *(const short8*)&cb[boff[1][2 + f]]; }
    __builtin_amdgcn_s_setprio(1);
    #pragma unroll
    for (int fm = 0; fm < 4; ++fm)
      #pragma unroll
      for (int fn = 0; fn < 2; ++fn){
        acc[fm][2 + fn] = __builtin_amdgcn_mfma_f32_16x16x32_bf16(ah[fm][0], bh[fn][0], acc[fm][2 + fn], 0, 0, 0);
        acc[fm][2 + fn] = __builtin_amdgcn_mfma_f32_16x16x32_bf16(ah[fm][1], bh[fn][1], acc[fm][2 + fn], 0, 0, 0);
      }
    __builtin_amdgcn_s_setprio(0);
    __builtin_amdgcn_sched_barrier(0);
    __builtin_amdgcn_s_barrier();
    __builtin_amdgcn_sched_barrier(0);

    // ---- ph2: (fmH, fnH) ----
    if (t < 6) STG_AFML(bc, kn2)
    #pragma unroll
    for (int f = 0; f < 4; ++f){ ah[f][0] = *(const short8*)&cb[aoff[0][4 + f]]; ah[f][1] = *(const short8*)&cb[aoff[1][4 + f]]; }
    __builtin_amdgcn_s_setprio(1);
    #pragma unroll
    for (int fm = 0; fm < 4; ++fm)
      #pragma unroll
      for (int fn = 0; fn < 2; ++fn){
        acc[4 + fm][2 + fn] = __builtin_amdgcn_mfma_f32_16x16x32_bf16(ah[fm][0], bh[fn][0], acc[4 + fm][2 + fn], 0, 0, 0);
        acc[4 + fm][2 + fn] = __builtin_amdgcn_mfma_f32_16x16x32_bf16(ah[fm][1], bh[fn][1], acc[4 + fm][2 + fn], 0, 0, 0);
      }
    __builtin_amdgcn_s_setprio(0);
    __builtin_amdgcn_sched_barrier(0);
    __builtin_amdgcn_s_barrier();
    __builtin_amdgcn_sched_barrier(0);

    // ---- ph3: (fmH, fnL) ----
    if (t < 6) STG_BFNH(bc, kn2)
    #pragma unroll
    for (int f = 0; f < 2; ++f){ bh[f][0] = *(const short8*)&cb[boff[0][f]]; bh[f][1] = *(const short8*)&cb[boff[1][f]]; }
    __builtin_amdgcn_s_setprio(1);
    #pragma unroll
    for (int fm = 0; fm < 4; ++fm)
      #pragma unroll
      for (int fn = 0; fn < 2; ++fn){
        acc[4 + fm][fn] = __builtin_amdgcn_mfma_f32_16x16x32_bf16(ah[fm][0], bh[fn][0], acc[4 + fm][fn], 0, 0, 0);
        acc[4 + fm][fn] = __builtin_amdgcn_mfma_f32_16x16x32_bf16(ah[fm][1], bh[fn][1], acc[4 + fm][fn], 0, 0, 0);
      }
    __builtin_amdgcn_s_setprio(0);
    __builtin_amdgcn_sched_barrier(0);
    if (t < 6) waitv4(); else if (t == 6) waitv0();
    __builtin_amdgcn_s_barrier();
    __builtin_amdgcn_sched_barrier(0);
  }

  // ---- fused argmin epilogue ----
  __syncthreads();
  u64 best[4];
  #pragma unroll
  for (int fn = 0; fn < 4; ++fn){
    u64 bk = ~0ull;
    #pragma unroll
    for (int fm = 0; fm < 8; ++fm){
      #pragma unroll
      for (int j = 0; j < 4; ++j){
        int v = m0 + wm * 128 + fm * 16 + (lane >> 4) * 4 + j;
        float sc = cnorm[v] - 2.0f * acc[fm][fn][j];
        u32 o = __float_as_uint(sc);
        o = (o & 0x80000000u) ? ~o : (o | 0x80000000u);
        bk = umin64(bk, ((u64)o << 32) | (u32)v);
      }
    }
    bk = umin64(bk, shfl_xor_u64(bk, 16));
    bk = umin64(bk, shfl_xor_u64(bk, 32));
    best[fn] = bk;
  }
  u64* kbuf = (u64*)&lds[0][0];
  if (lane < 16){
    #pragma unroll
    for (int fn = 0; fn < 4; ++fn)
      kbuf[wm * 256 + wn * 64 + fn * 16 + lane] = best[fn];
  }
  __syncthreads();
  if (tid < 256){
    u64 k2 = umin64(kbuf[tid], kbuf[256 + tid]);
    atomicMin((unsigned long long*)(okeys + bbase + tid), (unsigned long long)k2);
  }
#undef STG_AFML
#undef STG_AFMH
#undef STG_BFNL
#undef STG_BFNH
}

extern "C" void kernel_launch(void* const* d_in, const int* in_sizes, int n_in,
                              void* d_out, int out_size, void* d_ws, size_t ws_size,
                              hipStream_t stream){
  const float* x      = (const float*)d_in[0];
  const float* pre_w  = (const float*)d_in[1];
  const float* pre_b  = (const float*)d_in[2];
  const float* emb    = (const float*)d_in[3];
  const float* post_w = (const float*)d_in[4];
  const float* post_b = (const float*)d_in[5];

  float* z_out   = (float*)d_out;              // [256][512][256]
  float* zq_out  = z_out + 33554432;           // [256][512][256]
  float* rec_out = z_out + 67108864;           // [256][512][256]

  char* w = (char*)d_ws;
  u16* prew_b  = (u16*)(w);                    // 512KB
  u16* postw_b = (u16*)(w + 524288);           // 512KB
  u16* emb_b   = (u16*)(w + 1048576);          // 4MB
  float* cnorm = (float*)(w + 5242880);        // 16KB
  u64* keys    = (u64*)(w + 5259264);          // 512KB
  u16* xb      = (u16*)(w + 5783552);          // 64MB [65536][512] bf16
  u16* zb = xb;                                // z^T bf16 aliases xb (disjoint lifetime)

  k_cvt  <<<1024, 256, 0, stream>>>(pre_w, prew_b, 262144);
  k_cvt  <<<1024, 256, 0, stream>>>(post_w, postw_b, 262144);
  k_cvt  <<<8192, 256, 0, stream>>>(emb, emb_b, 2097152);
  k_cnorm<<<4096, 64, 0, stream>>>(emb, cnorm);
  hipMemsetAsync(keys, 0xFF, 65536 * sizeof(u64), stream);

  // x [b][c][s] -> xb [b][s][c]
  k_tcvt<<<8192, 256, 0, stream>>>(x, xb);

  // GEMM1: z = pre_w * x + pre_b
  k_gemm<0><<<256 * 2 * 4, 256, 0, stream>>>(prew_b, xb,
      nullptr, pre_b, nullptr, z_out, nullptr, 512, 2);

  // z [b][e][s] -> zb [b][s][e]
  k_tcvt<<<8192, 256, 0, stream>>>(z_out, zb);

  // GEMM2: 256x256 phase-pipelined scores + fused argmin -> keys
  k_gemm2<<<256 * 16, 512, 0, stream>>>(emb_b, zb, cnorm, keys);

  // z_q gather (exact f32)
  k_zq<<<1024, 64, 0, stream>>>(keys, emb, zq_out);

  // GEMM3: rec = post_w * z_q + post_b  (B staged by gathering emb_b rows via tokens)
  k_gemm<2><<<256 * 2 * 4, 256, 0, stream>>>(postw_b, emb_b,
      keys, post_b, nullptr, rec_out, nullptr, 512, 2);
}

// Round 4
// 546.750 us; speedup vs baseline: 1.8306x; 1.0039x over previous
//
#include <hip/hip_runtime.h>
#include <hip/hip_bf16.h>

typedef unsigned short u16;
typedef unsigned int   u32;
typedef unsigned long long u64;

using short8 = __attribute__((ext_vector_type(8))) short;
using f32x4  = __attribute__((ext_vector_type(4))) float;
using u16x8  = __attribute__((ext_vector_type(8))) unsigned short;

#define AS_GLOBAL __attribute__((address_space(1)))
#define AS_LDS    __attribute__((address_space(3)))

// ---- bf16 helpers (manual RNE) ----
__device__ __forceinline__ u16 f2b(float x){
  u32 u = __float_as_uint(x);
  u32 r = (u + 0x7FFFu + ((u >> 16) & 1u)) >> 16;
  return (u16)r;
}
__device__ __forceinline__ float b2f(u16 h){ return __uint_as_float(((u32)h) << 16); }

__device__ __forceinline__ void gload16(u16* l, const u16* g){
  __builtin_amdgcn_global_load_lds((const AS_GLOBAL u32*)g, (AS_LDS u32*)l, 16, 0, 0);
}

__device__ __forceinline__ u64 umin64(u64 a, u64 b){ return a < b ? a : b; }

__device__ __forceinline__ u64 shfl_xor_u64(u64 v, int m){
  u32 lo = __shfl_xor((u32)v, m, 64);
  u32 hi = __shfl_xor((u32)(v >> 32), m, 64);
  return ((u64)hi << 32) | lo;
}

// ---- prep kernels ----
__global__ void k_cvt(const float* __restrict__ w, u16* __restrict__ d, int n){
  int i = blockIdx.x * 256 + threadIdx.x;
  if (i < n) d[i] = f2b(w[i]);
}

__global__ void k_cnorm(const float* __restrict__ emb, float* __restrict__ cnorm){
  int v = blockIdx.x, lane = threadIdx.x;
  const float* r = emb + (size_t)v * 512;
  float s = 0.f;
  #pragma unroll
  for (int i = 0; i < 8; ++i){ float x = r[lane + i * 64]; s += x * x; }
  #pragma unroll
  for (int off = 32; off; off >>= 1) s += __shfl_down(s, off, 64);
  if (lane == 0) cnorm[v] = s;
}

// ---- transpose+convert: src f32 [256 b][512 r][256 c] -> d bf16 [b][c][r] ----
__global__ void k_tcvt(const float* __restrict__ src, u16* __restrict__ d){
  __shared__ float t[64][65];
  const int bid = blockIdx.x;
  const int b  = bid >> 5;
  const int rb = (bid >> 2) & 7;
  const int cb = bid & 3;
  const float* s = src + ((size_t)b * 512 + (size_t)rb * 64) * 256 + cb * 64;
  const int tid = threadIdx.x;
  #pragma unroll
  for (int j = 0; j < 4; ++j){
    int fl = j * 256 + tid;
    int r = fl >> 4, c4 = (fl & 15) * 4;
    float4 v = *(const float4*)(s + (size_t)r * 256 + c4);
    t[r][c4 + 0] = v.x; t[r][c4 + 1] = v.y; t[r][c4 + 2] = v.z; t[r][c4 + 3] = v.w;
  }
  __syncthreads();
  u16* o = d + ((size_t)b * 256 + (size_t)cb * 64) * 512 + rb * 64;
  #pragma unroll
  for (int j = 0; j < 2; ++j){
    int fl = j * 256 + tid;
    int c = fl >> 3, r8 = (fl & 7) * 8;
    u16x8 hv;
    #pragma unroll
    for (int i = 0; i < 8; ++i) hv[i] = f2b(t[r8 + i][c]);
    *(u16x8*)(o + (size_t)c * 512 + r8) = hv;
  }
}

// ---- z_q gather ----
__global__ void k_zq(const u64* __restrict__ keys, const float* __restrict__ emb, float* __restrict__ zq){
  int sidx = blockIdx.x * 64 + threadIdx.x;
  int b = sidx >> 8, s = sidx & 255;
  int v = (int)(u32)keys[sidx];
  const float4* er = (const float4*)(emb + (size_t)v * 512);
  float* o = zq + (size_t)b * 512 * 256 + s;
  #pragma unroll 4
  for (int e4 = 0; e4 < 128; ++e4){
    float4 vv = er[e4];
    o[(size_t)(e4 * 4 + 0) * 256] = vv.x;
    o[(size_t)(e4 * 4 + 1) * 256] = vv.y;
    o[(size_t)(e4 * 4 + 2) * 256] = vv.z;
    o[(size_t)(e4 * 4 + 3) * 256] = vv.w;
  }
}

// ---- small GEMM (proven 128x128 2-phase): GEMM1 & GEMM3 ----
template<int MODE>
__global__ __launch_bounds__(256, 4) void k_gemm(
    const u16* __restrict__ Ah,
    const u16* __restrict__ Bh,
    const u64* __restrict__ gkeys,
    const float* __restrict__ bias,
    float* __restrict__ Cout,
    int M, int mtbits)
{
  constexpr int K = 512;
  __shared__ __align__(16) u16 sA[128 * 64];
  __shared__ __align__(16) u16 sB[128 * 64];

  const int tid  = threadIdx.x;
  const int lane = tid & 63;
  const int wid  = tid >> 6;
  const int wm = wid >> 1, wn = wid & 1;

  const int nwg = gridDim.x;
  const int chunk = nwg >> 3;
  const int pb = blockIdx.x;
  const int bid = (pb & 7) * chunk + (pb >> 3);

  const int mt = bid & ((1 << mtbits) - 1);
  const int nt = (bid >> mtbits) & 1;
  const int b  = bid >> (mtbits + 1);
  const int m0 = mt * 128;
  const int n0 = nt * 128;
  const int bbase = b * 256;

  const u16* ga[4];
  const u16* gb[4];
  int ldso[4];
  #pragma unroll
  for (int i = 0; i < 4; ++i){
    int e = i * 256 + tid;
    int r = e >> 3;
    int sl = (e & 7) ^ (r & 7);
    ldso[i] = e * 8;
    ga[i] = Ah + (size_t)(m0 + r) * K + sl * 8;
    size_t brow;
    if (MODE == 2) brow = (size_t)(u32)gkeys[bbase + n0 + r];
    else           brow = (size_t)(bbase + n0 + r);
    gb[i] = Bh + brow * K + sl * 8;
  }

  const f32x4 zero4 = {0.f, 0.f, 0.f, 0.f};
  f32x4 acc[4][4];
  #pragma unroll
  for (int i = 0; i < 4; ++i)
    #pragma unroll
    for (int j = 0; j < 4; ++j) acc[i][j] = zero4;

  int aoff[2][4], boff[2][4];
  #pragma unroll
  for (int ks = 0; ks < 2; ++ks)
    #pragma unroll
    for (int f = 0; f < 4; ++f){
      int rA = wm * 64 + f * 16 + (lane & 15);
      aoff[ks][f] = rA * 64 + (((ks * 4 + (lane >> 4)) ^ (rA & 7)) * 8);
      int rB = wn * 64 + f * 16 + (lane & 15);
      boff[ks][f] = rB * 64 + (((ks * 4 + (lane >> 4)) ^ (rB & 7)) * 8);
    }

  for (int kt = 0; kt < 8; ++kt){
    const int k0 = kt * 64;
    #pragma unroll
    for (int i = 0; i < 4; ++i){
      gload16(&sA[ldso[i]], ga[i] + k0);
      gload16(&sB[ldso[i]], gb[i] + k0);
    }
    __syncthreads();
    #pragma unroll
    for (int ks = 0; ks < 2; ++ks){
      short8 ah[4], bh[4];
      #pragma unroll
      for (int f = 0; f < 4; ++f){
        ah[f] = *(const short8*)&sA[aoff[ks][f]];
        bh[f] = *(const short8*)&sB[boff[ks][f]];
      }
      #pragma unroll
      for (int fm = 0; fm < 4; ++fm)
        #pragma unroll
        for (int fn = 0; fn < 4; ++fn)
          acc[fm][fn] = __builtin_amdgcn_mfma_f32_16x16x32_bf16(ah[fm], bh[fn], acc[fm][fn], 0, 0, 0);
    }
    __syncthreads();
  }

  const int row0 = m0 + wm * 64;
  const int col  = n0 + wn * 64 + (lane & 15);
  float* Cb = Cout + (size_t)b * M * 256;
  #pragma unroll
  for (int fm = 0; fm < 4; ++fm){
    #pragma unroll
    for (int j = 0; j < 4; ++j){
      int row = row0 + fm * 16 + (lane >> 4) * 4 + j;
      float bi = bias[row];
      #pragma unroll
      for (int fn = 0; fn < 4; ++fn)
        Cb[(size_t)row * 256 + col + fn * 16] = acc[fm][fn][j] + bi;
    }
  }
}

// ---- GEMM2: persistent per-batch block, continuous 128-tile pipeline ----
// One block per b (256 blocks = 1/CU). Sweeps mt=0..15, kt=0..7 as a single
// tile stream tau=0..127. Per phase: 1 stage region (2 gloads) + 16 MFMA.
// Regions: AfmL/AfmH/BfnL/BfnH, each read in exactly one phase (B frags held
// in regs ph0->ph3). Stage map: ph0(t)->AfmH(t+1), ph1(t)->AfmL(t+2),
// ph2(t)->BfnL(t+2), ph3(t)->BfnH(t+2).
// vmcnt accounting (2 gloads/stage, steady outstanding 12, drain 2/phase):
//  before ph0(t): oldest = BfnL(t)  [issued ph2(t-2)] -> vmcnt(10) drains it
//  before ph1(t): oldest = BfnH(t)  [ph3(t-2)]        -> vmcnt(10)
//  before ph2(t): oldest = AfmH(t)  [ph0(t-1)]        -> vmcnt(10)
//  before ph3(t): oldest = AfmL(t+1) (early, harmless) -> vmcnt(10)
// Region write-safety: each stage's dest was last read >=1 barrier earlier.
// Tail (tau>=126): vmcnt(0). Argmin: running reg min across all mt, no atomics.
__global__ __launch_bounds__(512, 2) void k_gemm2(
    const u16* __restrict__ Ah,      // emb_b [4096][512]
    const u16* __restrict__ Bh,      // zb [65536][512]
    const float* __restrict__ cnorm,
    u64* __restrict__ okeys)
{
  __shared__ __align__(16) u16 lds[75776];  // 0..65535 stage(2x32KB), 65536..73727 cnorm(16KB), 73728.. kbuf(4KB)

  const int tid  = threadIdx.x;
  const int lane = tid & 63;
  const int wid  = tid >> 6;
  const int wm   = wid >> 2;
  const int wn   = wid & 3;
  const int b    = blockIdx.x;
  const int bbase = b * 256;

  // cnorm -> LDS (drained before staging begins)
  float* cn = (float*)&lds[65536];
  {
    const float4* c4 = (const float4*)cnorm;
    float4 a0 = c4[tid], a1 = c4[tid + 512];
    ((float4*)cn)[tid] = a0; ((float4*)cn)[tid + 512] = a1;
  }
  __syncthreads();

  // staging geometry (proven swizzle: LDS[r][s] = G[r][s ^ (r&7)])
  const int l8 = lane >> 3;
  const int sl = (lane & 7) ^ l8;
  const int arb = (wid < 4) ? wid * 16 : 128 + (wid - 4) * 16;   // AfmL rows {0-63,128-191}
  const int brb = (wid >> 1) * 64 + (wid & 1) * 16;              // BfnL rows {g*64+0..31}
  const size_t aS = (size_t)(arb + l8) * 512 + sl * 8;
  const size_t bS = (size_t)(bbase + brb + l8) * 512 + sl * 8;
  const int dA = arb * 64 + lane * 8;
  const int dB = 16384 + brb * 64 + lane * 8;

#define STG_AFML(tp) if ((tp) < 128){ const u16* s_ = Ah + (size_t)((tp) >> 3) * 131072 + aS + ((tp) & 7) * 64; u16* d_ = &lds[((tp) & 1) * 32768 + dA]; gload16(d_, s_); gload16(d_ + 512, s_ + 4096); }
#define STG_AFMH(tp) if ((tp) < 128){ const u16* s_ = Ah + (size_t)((tp) >> 3) * 131072 + aS + 32768 + ((tp) & 7) * 64; u16* d_ = &lds[((tp) & 1) * 32768 + dA + 4096]; gload16(d_, s_); gload16(d_ + 512, s_ + 4096); }
#define STG_BFNL(tp) if ((tp) < 128){ const u16* s_ = Bh + bS + ((tp) & 7) * 64; u16* d_ = &lds[((tp) & 1) * 32768 + dB]; gload16(d_, s_); gload16(d_ + 512, s_ + 4096); }
#define STG_BFNH(tp) if ((tp) < 128){ const u16* s_ = Bh + bS + 16384 + ((tp) & 7) * 64; u16* d_ = &lds[((tp) & 1) * 32768 + dB + 2048]; gload16(d_, s_); gload16(d_ + 512, s_ + 4096); }

#define PH_WAIT(tau_) { if ((tau_) < 126){ asm volatile("s_waitcnt vmcnt(10)" ::: "memory"); } else { asm volatile("s_waitcnt vmcnt(0)" ::: "memory"); } \
  __builtin_amdgcn_s_barrier(); __builtin_amdgcn_sched_barrier(0); }

  int aoff[2][8], boff[2][4];
  #pragma unroll
  for (int ks = 0; ks < 2; ++ks){
    #pragma unroll
    for (int f = 0; f < 8; ++f){
      int rA = wm * 128 + f * 16 + (lane & 15);
      aoff[ks][f] = rA * 64 + (((ks * 4 + (lane >> 4)) ^ (rA & 7)) * 8);
    }
    #pragma unroll
    for (int f = 0; f < 4; ++f){
      int rB = wn * 64 + f * 16 + (lane & 15);
      boff[ks][f] = 16384 + rB * 64 + (((ks * 4 + (lane >> 4)) ^ (rB & 7)) * 8);
    }
  }

  const f32x4 zero4 = {0.f, 0.f, 0.f, 0.f};
  f32x4 acc[8][4];
  #pragma unroll
  for (int i = 0; i < 8; ++i)
    #pragma unroll
    for (int j = 0; j < 4; ++j) acc[i][j] = zero4;

  u64 best[4];
  #pragma unroll
  for (int i = 0; i < 4; ++i) best[i] = ~0ull;

  short8 ah[4][2], bhL[2][2], bhH[2][2];

  // prologue: issue order matches steady-state oldest-first accounting
  STG_AFML(0) STG_BFNL(0) STG_BFNH(0) STG_AFMH(0)
  STG_AFML(1) STG_BFNL(1) STG_BFNH(1)

  for (int mt = 0; mt < 16; ++mt){
    #pragma unroll 2
    for (int kt = 0; kt < 8; ++kt){
      const int tau = mt * 8 + kt;
      const int bb_ = (tau & 1) * 32768;

      // ---- ph0: Q00 (fmL x fnL) ----
      PH_WAIT(tau);
      STG_AFMH(tau + 1)
      #pragma unroll
      for (int f = 0; f < 4; ++f){ ah[f][0] = *(const short8*)&lds[bb_ + aoff[0][f]]; ah[f][1] = *(const short8*)&lds[bb_ + aoff[1][f]]; }
      #pragma unroll
      for (int f = 0; f < 2; ++f){ bhL[f][0] = *(const short8*)&lds[bb_ + boff[0][f]]; bhL[f][1] = *(const short8*)&lds[bb_ + boff[1][f]]; }
      __builtin_amdgcn_s_setprio(1);
      #pragma unroll
      for (int fm = 0; fm < 4; ++fm)
        #pragma unroll
        for (int fn = 0; fn < 2; ++fn){
          acc[fm][fn] = __builtin_amdgcn_mfma_f32_16x16x32_bf16(ah[fm][0], bhL[fn][0], acc[fm][fn], 0, 0, 0);
          acc[fm][fn] = __builtin_amdgcn_mfma_f32_16x16x32_bf16(ah[fm][1], bhL[fn][1], acc[fm][fn], 0, 0, 0);
        }
      __builtin_amdgcn_s_setprio(0);
      __builtin_amdgcn_sched_barrier(0);

      // ---- ph1: Q01 (fmL x fnH), A held ----
      PH_WAIT(tau);
      STG_AFML(tau + 2)
      #pragma unroll
      for (int f = 0; f < 2; ++f){ bhH[f][0] = *(const short8*)&lds[bb_ + boff[0][2 + f]]; bhH[f][1] = *(const short8*)&lds[bb_ + boff[1][2 + f]]; }
      __builtin_amdgcn_s_setprio(1);
      #pragma unroll
      for (int fm = 0; fm < 4; ++fm)
        #pragma unroll
        for (int fn = 0; fn < 2; ++fn){
          acc[fm][2 + fn] = __builtin_amdgcn_mfma_f32_16x16x32_bf16(ah[fm][0], bhH[fn][0], acc[fm][2 + fn], 0, 0, 0);
          acc[fm][2 + fn] = __builtin_amdgcn_mfma_f32_16x16x32_bf16(ah[fm][1], bhH[fn][1], acc[fm][2 + fn], 0, 0, 0);
        }
      __builtin_amdgcn_s_setprio(0);
      __builtin_amdgcn_sched_barrier(0);

      // ---- ph2: Q11 (fmH x fnH), B held ----
      PH_WAIT(tau);
      STG_BFNL(tau + 2)
      #pragma unroll
      for (int f = 0; f < 4; ++f){ ah[f][0] = *(const short8*)&lds[bb_ + aoff[0][4 + f]]; ah[f][1] = *(const short8*)&lds[bb_ + aoff[1][4 + f]]; }
      __builtin_amdgcn_s_setprio(1);
      #pragma unroll
      for (int fm = 0; fm < 4; ++fm)
        #pragma unroll
        for (int fn = 0; fn < 2; ++fn){
          acc[4 + fm][2 + fn] = __builtin_amdgcn_mfma_f32_16x16x32_bf16(ah[fm][0], bhH[fn][0], acc[4 + fm][2 + fn], 0, 0, 0);
          acc[4 + fm][2 + fn] = __builtin_amdgcn_mfma_f32_16x16x32_bf16(ah[fm][1], bhH[fn][1], acc[4 + fm][2 + fn], 0, 0, 0);
        }
      __builtin_amdgcn_s_setprio(0);
      __builtin_amdgcn_sched_barrier(0);

      // ---- ph3: Q10 (fmH x fnL), A+B held, no LDS reads ----
      PH_WAIT(tau);
      STG_BFNH(tau + 2)
      __builtin_amdgcn_s_setprio(1);
      #pragma unroll
      for (int fm = 0; fm < 4; ++fm)
        #pragma unroll
        for (int fn = 0; fn < 2; ++fn){
          acc[4 + fm][fn] = __builtin_amdgcn_mfma_f32_16x16x32_bf16(ah[fm][0], bhL[fn][0], acc[4 + fm][fn], 0, 0, 0);
          acc[4 + fm][fn] = __builtin_amdgcn_mfma_f32_16x16x32_bf16(ah[fm][1], bhL[fn][1], acc[4 + fm][fn], 0, 0, 0);
        }
      __builtin_amdgcn_s_setprio(0);
      __builtin_amdgcn_sched_barrier(0);
    }

    // per-mt epilogue: fold scores into running best (VALU only, no barriers)
    #pragma unroll
    for (int fn = 0; fn < 4; ++fn){
      #pragma unroll
      for (int fm = 0; fm < 8; ++fm){
        #pragma unroll
        for (int j = 0; j < 4; ++j){
          int v = mt * 256 + wm * 128 + fm * 16 + (lane >> 4) * 4 + j;
          float sc = cn[v] - 2.0f * acc[fm][fn][j];
          u32 o = __float_as_uint(sc);
          o = (o & 0x80000000u) ? ~o : (o | 0x80000000u);
          best[fn] = umin64(best[fn], ((u64)o << 32) | (u32)v);
        }
      }
    }
    #pragma unroll
    for (int i = 0; i < 8; ++i)
      #pragma unroll
      for (int j = 0; j < 4; ++j) acc[i][j] = zero4;
  }

  // block-level reduce + single store (no atomics)
  #pragma unroll
  for (int fn = 0; fn < 4; ++fn){
    best[fn] = umin64(best[fn], shfl_xor_u64(best[fn], 16));
    best[fn] = umin64(best[fn], shfl_xor_u64(best[fn], 32));
  }
  u64* kbuf = (u64*)&lds[73728];
  __syncthreads();
  if (lane < 16){
    #pragma unroll
    for (int fn = 0; fn < 4; ++fn)
      kbuf[wm * 256 + wn * 64 + fn * 16 + lane] = best[fn];
  }
  __syncthreads();
  if (tid < 256)
    okeys[bbase + tid] = umin64(kbuf[tid], kbuf[256 + tid]);

#undef STG_AFML
#undef STG_AFMH
#undef STG_BFNL
#undef STG_BFNH
#undef PH_WAIT
}

extern "C" void kernel_launch(void* const* d_in, const int* in_sizes, int n_in,
                              void* d_out, int out_size, void* d_ws, size_t ws_size,
                              hipStream_t stream){
  const float* x      = (const float*)d_in[0];
  const float* pre_w  = (const float*)d_in[1];
  const float* pre_b  = (const float*)d_in[2];
  const float* emb    = (const float*)d_in[3];
  const float* post_w = (const float*)d_in[4];
  const float* post_b = (const float*)d_in[5];

  float* z_out   = (float*)d_out;              // [256][512][256]
  float* zq_out  = z_out + 33554432;           // [256][512][256]
  float* rec_out = z_out + 67108864;           // [256][512][256]

  char* w = (char*)d_ws;
  u16* prew_b  = (u16*)(w);                    // 512KB
  u16* postw_b = (u16*)(w + 524288);           // 512KB
  u16* emb_b   = (u16*)(w + 1048576);          // 4MB
  float* cnorm = (float*)(w + 5242880);        // 16KB
  u64* keys    = (u64*)(w + 5259264);          // 512KB
  u16* xb      = (u16*)(w + 5783552);          // 64MB [65536][512] bf16
  u16* zb = xb;                                // z^T bf16 aliases xb (disjoint lifetime)

  k_cvt  <<<1024, 256, 0, stream>>>(pre_w, prew_b, 262144);
  k_cvt  <<<1024, 256, 0, stream>>>(post_w, postw_b, 262144);
  k_cvt  <<<8192, 256, 0, stream>>>(emb, emb_b, 2097152);
  k_cnorm<<<4096, 64, 0, stream>>>(emb, cnorm);

  // x [b][c][s] -> xb [b][s][c]
  k_tcvt<<<8192, 256, 0, stream>>>(x, xb);

  // GEMM1: z = pre_w * x + pre_b
  k_gemm<0><<<256 * 2 * 4, 256, 0, stream>>>(prew_b, xb,
      nullptr, pre_b, z_out, 512, 2);

  // z [b][e][s] -> zb [b][s][e]
  k_tcvt<<<8192, 256, 0, stream>>>(z_out, zb);

  // GEMM2: persistent per-batch scores + argmin -> keys (writes all 65536)
  k_gemm2<<<256, 512, 0, stream>>>(emb_b, zb, cnorm, keys);

  // z_q gather (exact f32)
  k_zq<<<1024, 64, 0, stream>>>(keys, emb, zq_out);

  // GEMM3: rec = post_w * z_q + post_b  (B staged by gathering emb_b rows via tokens)
  k_gemm<2><<<256 * 2 * 4, 256, 0, stream>>>(postw_b, emb_b,
      keys, post_b, rec_out, 512, 2);
}